// Round 1
// baseline (167.992 us; speedup 1.0000x reference)
//
#include <hip/hip_runtime.h>

// SimpleEdgeModel fused implementation for MI355X (gfx950).
//
// Math: out[b,i,j] = Wo·relu(W3ᵀ·relu(W2ᵀ·relu(g[b,j]-g[b,i]+bc1)+bc2)+bc3)+bo
// with g = h@Wc1, h = node MLP(x).  Layer c1 is linear => folded into per-node g.
// Layers c2/c3 run as f16 MFMA (16x16x32), everything else fp32.

typedef _Float16 half_t;
typedef __attribute__((ext_vector_type(8))) _Float16 f16x8;
typedef __attribute__((ext_vector_type(4))) float f32x4;

// ---------------------------------------------------------------------------
// Kernel 1: per-node MLP.  h1=relu(x@Wa+ba); h2=relu(h1@Wb+bb); g=h2@Wc1.
// 1024 nodes, 4 nodes/block, 256 blocks x 256 threads. fp32, register-tiled 2x.
// ---------------------------------------------------------------------------
__global__ __launch_bounds__(256) void node_kernel(
    const float* __restrict__ x, const float* __restrict__ Wa, const float* __restrict__ ba,
    const float* __restrict__ Wb, const float* __restrict__ bb, const float* __restrict__ Wc1,
    float* __restrict__ g)
{
  __shared__ float sx[4 * 64];
  __shared__ float sh[4 * 128];
  __shared__ float sh2[4 * 128];
  const int t = threadIdx.x;
  const int node0 = blockIdx.x * 4;

  sx[t] = x[node0 * 64 + t];          // 4 rows of 64 floats
  __syncthreads();

  const int col = t & 127, ndg = t >> 7;   // 2 nodes per thread
  float a0 = ba[col], a1 = a0;
  #pragma unroll
  for (int cc = 0; cc < 64; cc++) {
    const float wv = Wa[cc * 128 + col];
    a0 = fmaf(sx[(2 * ndg + 0) * 64 + cc], wv, a0);
    a1 = fmaf(sx[(2 * ndg + 1) * 64 + cc], wv, a1);
  }
  sh[(2 * ndg + 0) * 128 + col] = fmaxf(a0, 0.f);
  sh[(2 * ndg + 1) * 128 + col] = fmaxf(a1, 0.f);
  __syncthreads();

  float b0 = bb[col], b1 = b0;
  #pragma unroll
  for (int k = 0; k < 128; k++) {
    const float wv = Wb[k * 128 + col];
    b0 = fmaf(sh[(2 * ndg + 0) * 128 + k], wv, b0);
    b1 = fmaf(sh[(2 * ndg + 1) * 128 + k], wv, b1);
  }
  sh2[(2 * ndg + 0) * 128 + col] = fmaxf(b0, 0.f);
  sh2[(2 * ndg + 1) * 128 + col] = fmaxf(b1, 0.f);
  __syncthreads();

  float c0 = 0.f, c1 = 0.f;
  #pragma unroll
  for (int k = 0; k < 128; k++) {
    const float wv = Wc1[k * 128 + col];
    c0 = fmaf(sh2[(2 * ndg + 0) * 128 + k], wv, c0);
    c1 = fmaf(sh2[(2 * ndg + 1) * 128 + k], wv, c1);
  }
  g[(node0 + 2 * ndg + 0) * 128 + col] = c0;   // NOTE: no bc1 here (added in e1)
  g[(node0 + 2 * ndg + 1) * 128 + col] = c1;
}

// ---------------------------------------------------------------------------
// Kernel 2: pack Wc2/Wc3 (fp32 [k][n]) into f16 MFMA B-fragment order:
// frag(nt,ks) is 512 f16 (1KB), element idx = L*8+j holds W[ks*32+(L>>4)*8+j][nt*16+(L&15)].
// ds_read_b128 at lane*16 is then conflict-free (stride 4 dwords).
// ---------------------------------------------------------------------------
__global__ __launch_bounds__(256) void wprep_kernel(
    const float* __restrict__ Wc2, const float* __restrict__ Wc3,
    half_t* __restrict__ W2f, half_t* __restrict__ W3f)
{
  const int bid = blockIdx.x;          // 0..15: layer(1b) x ntile(3b)
  const int layer = bid >> 3, nt = bid & 7;
  const int t = threadIdx.x;
  const int ks = t >> 6, L = t & 63;
  const float* src = layer ? Wc3 : Wc2;
  half_t* dst = layer ? W3f : W2f;
  #pragma unroll
  for (int j = 0; j < 8; j++) {
    const int k = ks * 32 + (L >> 4) * 8 + j;
    const int n = nt * 16 + (L & 15);
    dst[(nt * 4 + ks) * 512 + L * 8 + j] = (half_t)src[k * 128 + n];
  }
}

// ---------------------------------------------------------------------------
// Kernel 3: edge kernel. Block = (b, i, 128-wide j-tile); 4 waves x 32 rows.
// e1 = relu(g_j - g_i + bc1) built directly in A-frag layout (fp32 sources);
// layer2/layer3 = f16 MFMA 16x16x32, 2 Mtiles x 8 Ntiles per wave;
// e2 transposed C->A layout via in-place LDS scalar writes (wave-private rows);
// epilogue = relu, xWo, shfl_xor reduce over 16 cols, +bo, store.
// LDS: sW 32KB (W2 then W3) + sA 32KB = 64KB exactly -> 2 blocks/CU.
// ---------------------------------------------------------------------------
__global__ __launch_bounds__(256, 2) void edge_kernel(
    const float* __restrict__ g, const half_t* __restrict__ W2f, const half_t* __restrict__ W3f,
    const float* __restrict__ bc1, const float* __restrict__ bc2, const float* __restrict__ bc3,
    const float* __restrict__ Wo, const float* __restrict__ bo, float* __restrict__ out)
{
  __shared__ half_t sW[16384];   // 32KB, one layer's weights at a time
  __shared__ half_t sA[16384];   // 32KB, activations in A-frag layout

  const int t = threadIdx.x;
  const int lane = t & 63, w = t >> 6;
  const int q = lane >> 4, c = lane & 15;
  const int bid = blockIdx.x;
  const int b = bid >> 11, rem = bid & 2047, i = rem >> 2, j0 = (rem & 3) << 7;

  // ---- stage W2 -> sW (2048 float4, cooperative) ----
  {
    const float4* srcv = (const float4*)W2f;
    float4* dstv = (float4*)sW;
    #pragma unroll
    for (int r = 0; r < 8; r++) dstv[t + 256 * r] = srcv[t + 256 * r];
  }

  // ---- e1 -> sA in A-frag layout: A[m=lane&15][k=(lane>>4)*8+j] ----
  {
    const float* gB = g + (size_t)b * (512 * 128);
    const float* gi = gB + (size_t)i * 128;
    #pragma unroll
    for (int mt = 0; mt < 2; mt++) {
      const int mtg = w * 2 + mt;                 // global 16-row tile 0..7
      const int jrow = j0 + mtg * 16 + c;         // j index for this lane's row
      const float* gj = gB + (size_t)jrow * 128;
      #pragma unroll
      for (int ks = 0; ks < 4; ks++) {
        const int k0 = ks * 32 + q * 8;
        const float4 aj0 = *(const float4*)(gj + k0);
        const float4 aj1 = *(const float4*)(gj + k0 + 4);
        const float4 ai0 = *(const float4*)(gi + k0);
        const float4 ai1 = *(const float4*)(gi + k0 + 4);
        const float4 ab0 = *(const float4*)(bc1 + k0);
        const float4 ab1 = *(const float4*)(bc1 + k0 + 4);
        f16x8 v;
        v[0] = (half_t)fmaxf(aj0.x - ai0.x + ab0.x, 0.f);
        v[1] = (half_t)fmaxf(aj0.y - ai0.y + ab0.y, 0.f);
        v[2] = (half_t)fmaxf(aj0.z - ai0.z + ab0.z, 0.f);
        v[3] = (half_t)fmaxf(aj0.w - ai0.w + ab0.w, 0.f);
        v[4] = (half_t)fmaxf(aj1.x - ai1.x + ab1.x, 0.f);
        v[5] = (half_t)fmaxf(aj1.y - ai1.y + ab1.y, 0.f);
        v[6] = (half_t)fmaxf(aj1.z - ai1.z + ab1.z, 0.f);
        v[7] = (half_t)fmaxf(aj1.w - ai1.w + ab1.w, 0.f);
        *(f16x8*)(&sA[(mtg * 4 + ks) * 512 + lane * 8]) = v;
      }
    }
  }
  __syncthreads();

  const f32x4 zf = {0.f, 0.f, 0.f, 0.f};
  f32x4 acc0[8], acc1[8];
  #pragma unroll
  for (int nt = 0; nt < 8; nt++) { acc0[nt] = zf; acc1[nt] = zf; }

  // ---- layer 2 MFMA: e2 = e1 @ W2 ----
  #pragma unroll
  for (int ks = 0; ks < 4; ks++) {
    const f16x8 a0 = *(const f16x8*)(&sA[((w * 2 + 0) * 4 + ks) * 512 + lane * 8]);
    const f16x8 a1 = *(const f16x8*)(&sA[((w * 2 + 1) * 4 + ks) * 512 + lane * 8]);
    #pragma unroll
    for (int nt = 0; nt < 8; nt++) {
      const f16x8 bf = *(const f16x8*)(&sW[(nt * 4 + ks) * 512 + lane * 8]);
      acc0[nt] = __builtin_amdgcn_mfma_f32_16x16x32_f16(a0, bf, acc0[nt], 0, 0, 0);
      acc1[nt] = __builtin_amdgcn_mfma_f32_16x16x32_f16(a1, bf, acc1[nt], 0, 0, 0);
    }
  }

  // ---- e2 = relu(acc+bc2): C-layout (col=c,row=q*4+r) -> A-frag layout in sA ----
  // Wave-private rows: safe to overwrite own e1 frags (reads already consumed).
  {
    float bc2v[8];
    #pragma unroll
    for (int nt = 0; nt < 8; nt++) bc2v[nt] = bc2[nt * 16 + c];
    #pragma unroll
    for (int mt = 0; mt < 2; mt++) {
      #pragma unroll
      for (int nt = 0; nt < 8; nt++) {
        const f32x4 v = mt ? acc1[nt] : acc0[nt];
        const int kk = nt * 16 + c;               // layer-3 k index
        #pragma unroll
        for (int r = 0; r < 4; r++) {
          const float e = fmaxf(v[r] + bc2v[nt], 0.f);
          const int Lp = (q * 4 + r) + ((kk >> 3) & 3) * 16;
          sA[((w * 2 + mt) * 4 + (kk >> 5)) * 512 + Lp * 8 + (kk & 7)] = (half_t)e;
        }
      }
    }
  }
  __syncthreads();           // all waves done with W2 reads
  // ---- stage W3 -> sW ----
  {
    const float4* srcv = (const float4*)W3f;
    float4* dstv = (float4*)sW;
    #pragma unroll
    for (int r = 0; r < 8; r++) dstv[t + 256 * r] = srcv[t + 256 * r];
  }
  __syncthreads();

  #pragma unroll
  for (int nt = 0; nt < 8; nt++) { acc0[nt] = zf; acc1[nt] = zf; }

  // ---- layer 3 MFMA: e3 = e2 @ W3 ----
  #pragma unroll
  for (int ks = 0; ks < 4; ks++) {
    const f16x8 a0 = *(const f16x8*)(&sA[((w * 2 + 0) * 4 + ks) * 512 + lane * 8]);
    const f16x8 a1 = *(const f16x8*)(&sA[((w * 2 + 1) * 4 + ks) * 512 + lane * 8]);
    #pragma unroll
    for (int nt = 0; nt < 8; nt++) {
      const f16x8 bf = *(const f16x8*)(&sW[(nt * 4 + ks) * 512 + lane * 8]);
      acc0[nt] = __builtin_amdgcn_mfma_f32_16x16x32_f16(a0, bf, acc0[nt], 0, 0, 0);
      acc1[nt] = __builtin_amdgcn_mfma_f32_16x16x32_f16(a1, bf, acc1[nt], 0, 0, 0);
    }
  }

  // ---- epilogue: out[m] = sum_n relu(e3+bc3)[m][n]*Wo[n] + bo ----
  {
    float bc3v[8], wov[8];
    #pragma unroll
    for (int nt = 0; nt < 8; nt++) {
      bc3v[nt] = bc3[nt * 16 + c];
      wov[nt]  = Wo[nt * 16 + c];
    }
    const float bo0 = bo[0];
    float p0[4] = {0.f, 0.f, 0.f, 0.f}, p1[4] = {0.f, 0.f, 0.f, 0.f};
    #pragma unroll
    for (int nt = 0; nt < 8; nt++) {
      #pragma unroll
      for (int r = 0; r < 4; r++) {
        p0[r] += fmaxf(acc0[nt][r] + bc3v[nt], 0.f) * wov[nt];
        p1[r] += fmaxf(acc1[nt][r] + bc3v[nt], 0.f) * wov[nt];
      }
    }
    // reduce over the 16 col-lanes (c); masks<16 stay inside each q-group
    #pragma unroll
    for (int mask = 1; mask <= 8; mask <<= 1) {
      #pragma unroll
      for (int r = 0; r < 4; r++) {
        p0[r] += __shfl_xor(p0[r], mask, 64);
        p1[r] += __shfl_xor(p1[r], mask, 64);
      }
    }
    if (c == 0) {
      const size_t base = ((size_t)b * 512 + i) * 512 + j0;
      #pragma unroll
      for (int r = 0; r < 4; r++) {
        out[base + w * 32 +      q * 4 + r] = p0[r] + bo0;
        out[base + w * 32 + 16 + q * 4 + r] = p1[r] + bo0;
      }
    }
  }
}

// ---------------------------------------------------------------------------
extern "C" void kernel_launch(void* const* d_in, const int* in_sizes, int n_in,
                              void* d_out, int out_size, void* d_ws, size_t ws_size,
                              hipStream_t stream)
{
  const float* x   = (const float*)d_in[0];
  const float* Wa  = (const float*)d_in[1];
  const float* ba  = (const float*)d_in[2];
  const float* Wb  = (const float*)d_in[3];
  const float* bb  = (const float*)d_in[4];
  const float* Wc1 = (const float*)d_in[5];
  const float* bc1 = (const float*)d_in[6];
  const float* Wc2 = (const float*)d_in[7];
  const float* bc2 = (const float*)d_in[8];
  const float* Wc3 = (const float*)d_in[9];
  const float* bc3 = (const float*)d_in[10];
  const float* Wo  = (const float*)d_in[11];
  const float* bo  = (const float*)d_in[12];
  float* out = (float*)d_out;

  // workspace layout: g (1024x128 f32, 512KB) | W2f (32KB f16) | W3f (32KB f16)
  char* ws = (char*)d_ws;
  float*  gbuf = (float*)ws;
  half_t* W2f  = (half_t*)(ws + 524288);
  half_t* W3f  = (half_t*)(ws + 524288 + 32768);

  node_kernel<<<256, 256, 0, stream>>>(x, Wa, ba, Wb, bb, Wc1, gbuf);
  wprep_kernel<<<16, 256, 0, stream>>>(Wc2, Wc3, W2f, W3f);
  edge_kernel<<<4096, 256, 0, stream>>>(gbuf, W2f, W3f, bc1, bc2, bc3, Wo, bo, out);
}